// Round 5
// baseline (1213.574 us; speedup 1.0000x reference)
//
#include <hip/hip_runtime.h>
#include <hip/hip_bf16.h>

#define Tn 8192
#define Dn 1024
#define Fn 4096
#define SHn 2048
#define En 16
#define CAPn 1024

typedef __bf16 bf16_t;
typedef bf16_t bf16x8 __attribute__((ext_vector_type(8)));
typedef float f32x4 __attribute__((ext_vector_type(4)));

__device__ __forceinline__ unsigned short f2bf(float f) {
  unsigned int u = __builtin_bit_cast(unsigned int, f);
  u += 0x7FFFu + ((u >> 16) & 1u);
  return (unsigned short)(u >> 16);
}
__device__ __forceinline__ unsigned int pack2(float a, float b) {
  return (unsigned int)f2bf(a) | ((unsigned int)f2bf(b) << 16);
}

__device__ __forceinline__ void gload16(const void* g, void* l) {
  __builtin_amdgcn_global_load_lds(
      (const __attribute__((address_space(1))) unsigned int*)g,
      (__attribute__((address_space(3))) unsigned int*)l, 16, 0, 0);
}

// ---------------- fp32 -> bf16 convert ----------------
__global__ __launch_bounds__(256) void kcvt(const float* __restrict__ s,
                                            unsigned short* __restrict__ d, int n8) {
  int i = blockIdx.x * 256 + threadIdx.x;
  int stride = gridDim.x * 256;
  const float4* sv = (const float4*)s;
  for (; i < n8; i += stride) {
    float4 a = sv[2 * i], b = sv[2 * i + 1];
    uint4 u = { pack2(a.x, a.y), pack2(a.z, a.w), pack2(b.x, b.y), pack2(b.z, b.w) };
    ((uint4*)d)[i] = u;
  }
}

// ---------------- gate scores: sigmoid(x @ gate_w^T), stored [E][T] ----------------
__global__ __launch_bounds__(256) void kscores(const float* __restrict__ x,
                                               const float* __restrict__ gw,
                                               float* __restrict__ sc) {
  __shared__ float sx[Dn];
  int tid = threadIdx.x, tok = blockIdx.x;
  ((float4*)sx)[tid] = ((const float4*)(x + (size_t)tok * Dn))[tid];
  __syncthreads();
  int e = tid >> 4, kl = tid & 15;
  const float4* w = (const float4*)(gw + e * Dn);
  const float4* xv = (const float4*)sx;
  float acc = 0.f;
#pragma unroll
  for (int j = 0; j < 16; ++j) {
    float4 a = w[kl + 16 * j], b = xv[kl + 16 * j];
    acc += a.x * b.x + a.y * b.y + a.z * b.z + a.w * b.w;
  }
#pragma unroll
  for (int off = 8; off; off >>= 1) acc += __shfl_xor(acc, off, 64);
  if (kl == 0) sc[(size_t)e * Tn + tok] = 1.f / (1.f + expf(-acc));
}

// ---------------- per-expert top-CAP radix select (ties: lowest index) ----------------
__global__ __launch_bounds__(256) void kselect(const float* __restrict__ scores,
                                               int* __restrict__ ids,
                                               float* __restrict__ oscore) {
  __shared__ unsigned int keys[Tn];
  __shared__ unsigned int hist[256];
  __shared__ unsigned int sh_prefix, sh_k, sh_cnt, sh_eq;
  __shared__ int eqlist[1024];
  const int tid = threadIdx.x, e = blockIdx.x;
  const float* row = scores + (size_t)e * Tn;
  for (int i = 0; i < Tn / 256; ++i)
    keys[tid + i * 256] = __float_as_uint(row[tid + i * 256]);
  if (tid == 0) { sh_prefix = 0u; sh_k = CAPn; }
  __syncthreads();
  for (int shift = 24; shift >= 0; shift -= 8) {
    hist[tid] = 0u;
    __syncthreads();
    unsigned int prefix = sh_prefix;
    unsigned int mask = (shift == 24) ? 0u : (0xFFFFFFFFu << (shift + 8));
    for (int i = 0; i < Tn / 256; ++i) {
      unsigned int kk = keys[tid + i * 256];
      if ((kk & mask) == prefix) atomicAdd(&hist[(kk >> shift) & 255], 1u);
    }
    __syncthreads();
    if (tid == 0) {
      unsigned int k = sh_k, c = 0; int b;
      for (b = 255; b >= 0; --b) { c += hist[b]; if (c >= k) break; }
      sh_k = k - (c - hist[b]);
      sh_prefix = prefix | ((unsigned int)b << shift);
    }
    __syncthreads();
  }
  const unsigned int thr = sh_prefix;
  if (tid == 0) { sh_cnt = 0u; sh_eq = 0u; }
  __syncthreads();
  const int base = e * CAPn;
  for (int i = 0; i < Tn / 256; ++i) {
    int t = tid + i * 256;
    unsigned int kk = keys[t];
    if (kk > thr) {
      unsigned int p = atomicAdd(&sh_cnt, 1u);
      ids[base + p] = t;
      oscore[base + p] = __uint_as_float(kk);
    } else if (kk == thr) {
      unsigned int p = atomicAdd(&sh_eq, 1u);
      if (p < 1024u) eqlist[p] = t;
    }
  }
  __syncthreads();
  if (tid == 0) {
    int need = CAPn - (int)sh_cnt;
    int m = (int)sh_eq; if (m > 1024) m = 1024;
    for (int j = 0; j < need; ++j) {
      int best = 1 << 30, bi = 0;
      for (int i2 = 0; i2 < m; ++i2)
        if (eqlist[i2] < best) { best = eqlist[i2]; bi = i2; }
      eqlist[bi] = 1 << 30;
      ids[base + (int)sh_cnt + j] = best;
      oscore[base + (int)sh_cnt + j] = __uint_as_float(thr);
    }
  }
}

// =====================================================================
// 8-phase (4 phases/K-tile) counted-vmcnt GEMM, 512 threads, 8 waves,
// BM=256, BK=64, double-buffered LDS. Per phase: {2 stage issues ||
// ds_read frags -> s_barrier -> lgkmcnt(0) -> setprio(1) MFMA setprio(0)
// -> s_barrier}. vmcnt(2) only at phase 0 (next-tile loads stay in
// flight). bm-fastest block order + XCD chunk swizzle.
// GLU: BN=128, two B operands. Down: BN=256 or 128, one B.
// EPI: 0 = GLU -> H bf16; 1 = dense fp32 store; 2 = scatter atomicAdd*score
// =====================================================================
template <int BN, int NOPS, bool GATHER, int EPI>
__global__ __launch_bounds__(512, 2) void kgemm8(
    const unsigned short* __restrict__ Ab, const int* __restrict__ idsg,
    const unsigned short* __restrict__ B1b, const unsigned short* __restrict__ B2b,
    const float* __restrict__ bias1, const float* __restrict__ bias2,
    const float* __restrict__ scg, void* __restrict__ OutV,
    int N, int Mz, int K, int MBc, int NBc) {
  constexpr int BM = 256;
  constexpr int NF = (BN / 4) / 16;          // per-wave n fragments
  constexpr int BRPW = BN / 8;               // B rows staged per wave
  constexpr int BISS = BRPW / 8;             // B stage issues per wave per op
  constexpr int NISS = 4 + BISS * NOPS;      // total stage issues per wave per tile
  constexpr unsigned A_OFF = 0;
  constexpr unsigned B1_OFF = 32768;
  constexpr unsigned B2_OFF = 32768u + (unsigned)BN * 128u;

  __shared__ alignas(16) unsigned char lds[2][65536];
  __shared__ int sIds[BM];
  __shared__ float sSc[BM];

  const int tid = threadIdx.x;
  const int lane = tid & 63, w = tid >> 6;
  const int wm = w >> 2, wn = w & 3;
  const int lrow = lane & 15, lk = lane >> 4;
  const int lr = lane >> 3, lc = lane & 7;
  const int srcb = ((lc ^ lr) << 4);

  const int nwg = gridDim.x;
  const int cpx = nwg >> 3;
  const int bid = blockIdx.x;
  const int swz = (bid & 7) * cpx + (bid >> 3);
  const int bm = swz % MBc;                      // bm fastest: slab sharers adjacent
  const int bn = (swz / MBc) % NBc;
  const int z  = swz / (NBc * MBc);
  const int row0 = bm * BM;

  if (tid < BM) {
    if (GATHER || EPI == 2) {
      sIds[tid] = idsg[z * CAPn + row0 + tid];
      if (EPI == 2) sSc[tid] = scg[z * CAPn + row0 + tid];
    }
  }
  __syncthreads();

  const size_t ks = (size_t)K * 2;  // row stride in bytes
  const unsigned char* Az = (const unsigned char*)Ab + (EPI == 2 ? (size_t)z * Mz * ks : 0);
  const unsigned char* B1z = (const unsigned char*)B1b + (size_t)z * N * ks;
  const unsigned char* B2z = (NOPS == 2) ? (const unsigned char*)B2b + (size_t)z * N * ks : nullptr;

  const unsigned char* aS[4];
#pragma unroll
  for (int i = 0; i < 4; ++i) {
    int rr = w * 32 + 8 * i + lr;
    size_t arow = GATHER ? (size_t)sIds[rr] : (size_t)(row0 + rr);
    aS[i] = Az + arow * ks + srcb;
  }
  const unsigned char* b1S[BISS];
  const unsigned char* b2S[BISS];
#pragma unroll
  for (int i = 0; i < BISS; ++i) {
    int rr = bn * BN + w * BRPW + 8 * i + lr;
    b1S[i] = B1z + (size_t)rr * ks + srcb;
    if (NOPS == 2) b2S[i] = B2z + (size_t)rr * ks + srcb;
  }

  auto STG = [&](int idx, unsigned char* buf, int kb) {
    if (idx < 4) {
      gload16(aS[idx] + kb, buf + A_OFF + (unsigned)(w * 32 + 8 * idx) * 128u);
    } else if (NOPS == 2) {
      if (idx < 4 + BISS)
        gload16(b1S[idx - 4] + kb, buf + B1_OFF + (unsigned)(w * BRPW + 8 * (idx - 4)) * 128u);
      else
        gload16(b2S[idx - 4 - BISS] + kb, buf + B2_OFF + (unsigned)(w * BRPW + 8 * (idx - 4 - BISS)) * 128u);
    } else {
      gload16(b1S[idx - 4] + kb, buf + B1_OFF + (unsigned)(w * BRPW + 8 * (idx - 4)) * 128u);
    }
  };

  f32x4 acc[NOPS][8][NF];
#pragma unroll
  for (int o = 0; o < NOPS; ++o)
#pragma unroll
    for (int m = 0; m < 8; ++m)
#pragma unroll
      for (int n = 0; n < NF; ++n) acc[o][m][n] = {0.f, 0.f, 0.f, 0.f};

  // prologue: stage tile 0 into lds[0]
#pragma unroll
  for (int i = 0; i < NISS; ++i) STG(i, lds[0], 0);

  const int NT = K >> 6;
  int c = 0;
  for (int t = 0; t < NT; ++t) {
    unsigned char* bufc = lds[c];
    unsigned char* bufn = lds[c ^ 1];
    const bool pre = (t + 1 < NT);
    const int kb = (t + 1) * 128;
    bf16x8 bv[NOPS][NF][2];
#pragma unroll
    for (int p = 0; p < 4; ++p) {
      // stage 2 issues for tile t+1 (A first: scattered rows get max cover)
      if (pre) {
        if (2 * p < NISS) STG(2 * p, bufn, kb);
        if (2 * p + 1 < NISS) STG(2 * p + 1, bufn, kb);
      }
      if (p == 0) {
        // tile-t data must be fully landed before first reads
        if (pre) asm volatile("s_waitcnt vmcnt(2)" ::: "memory");
        else     asm volatile("s_waitcnt vmcnt(0)" ::: "memory");
        __builtin_amdgcn_s_barrier();
        __builtin_amdgcn_sched_barrier(0);
#pragma unroll
        for (int o = 0; o < NOPS; ++o)
#pragma unroll
          for (int n = 0; n < NF; ++n)
#pragma unroll
            for (int kk = 0; kk < 2; ++kk) {
              unsigned off = (unsigned)(wn * (BN / 4) + n * 16 + lrow) * 128u +
                             ((unsigned)((kk * 4 + lk) ^ (lrow & 7)) << 4);
              bv[o][n][kk] = *(const bf16x8*)(bufc + (o ? B2_OFF : B1_OFF) + off);
            }
      }
      bf16x8 av[2][2];
#pragma unroll
      for (int mm = 0; mm < 2; ++mm)
#pragma unroll
        for (int kk = 0; kk < 2; ++kk) {
          unsigned off = (unsigned)(wm * 128 + p * 32 + mm * 16 + lrow) * 128u +
                         ((unsigned)((kk * 4 + lk) ^ (lrow & 7)) << 4);
          av[mm][kk] = *(const bf16x8*)(bufc + A_OFF + off);
        }
      if (p != 0) {
        __builtin_amdgcn_sched_barrier(0);
        __builtin_amdgcn_s_barrier();
      }
      asm volatile("s_waitcnt lgkmcnt(0)" ::: "memory");
      __builtin_amdgcn_sched_barrier(0);
      __builtin_amdgcn_s_setprio(1);
#pragma unroll
      for (int mm = 0; mm < 2; ++mm)
#pragma unroll
        for (int n = 0; n < NF; ++n)
#pragma unroll
          for (int kk = 0; kk < 2; ++kk) {
            acc[0][2 * p + mm][n] = __builtin_amdgcn_mfma_f32_16x16x32_bf16(
                av[mm][kk], bv[0][n][kk], acc[0][2 * p + mm][n], 0, 0, 0);
            if (NOPS == 2)
              acc[1][2 * p + mm][n] = __builtin_amdgcn_mfma_f32_16x16x32_bf16(
                  av[mm][kk], bv[1][n][kk], acc[1][2 * p + mm][n], 0, 0, 0);
          }
      __builtin_amdgcn_s_setprio(0);
      __builtin_amdgcn_sched_barrier(0);
      __builtin_amdgcn_s_barrier();
    }
    c ^= 1;
  }

  // ---------------- epilogue ----------------
  if (EPI == 0) {
    unsigned short* H = (unsigned short*)OutV;
#pragma unroll
    for (int n = 0; n < NF; ++n) {
      int col = bn * BN + wn * (BN / 4) + n * 16 + lrow;
      float bg = bias1 ? bias1[(size_t)z * N + col] : 0.f;
      float bu = bias2 ? bias2[(size_t)z * N + col] : 0.f;
#pragma unroll
      for (int mq = 0; mq < 8; ++mq) {
#pragma unroll
        for (int j = 0; j < 4; ++j) {
          float g = acc[0][mq][n][j] + bg;
          float u = (NOPS == 2 ? acc[1][mq][n][j] : 0.f) + bu;
          float h = g / (1.f + __expf(-g)) * u;
          int row = row0 + wm * 128 + mq * 16 + lk * 4 + j;
          H[(size_t)z * Mz * N + (size_t)row * N + col] = f2bf(h);
        }
      }
    }
  } else {
    float* Out = (float*)OutV;
#pragma unroll
    for (int n = 0; n < NF; ++n) {
      int col = bn * BN + wn * (BN / 4) + n * 16 + lrow;
      float bb = bias1 ? bias1[(size_t)z * N + col] : 0.f;
#pragma unroll
      for (int mq = 0; mq < 8; ++mq) {
#pragma unroll
        for (int j = 0; j < 4; ++j) {
          int rl = wm * 128 + mq * 16 + lk * 4 + j;
          float v = acc[0][mq][n][j] + bb;
          if (EPI == 2) {
            atomicAdd(Out + (size_t)sIds[rl] * Dn + col, sSc[rl] * v);
          } else {
            Out[(size_t)(row0 + rl) * Dn + col] = v;
          }
        }
      }
    }
  }
}

extern "C" void kernel_launch(void* const* d_in, const int* in_sizes, int n_in,
                              void* d_out, int out_size, void* d_ws, size_t ws_size,
                              hipStream_t stream) {
  const float* x      = (const float*)d_in[0];
  const float* gate_w = (const float*)d_in[1];
  const float* up_w   = (const float*)d_in[2];
  const float* up_b   = (const float*)d_in[3];
  const float* gw     = (const float*)d_in[4];
  const float* gb     = (const float*)d_in[5];
  const float* down_w = (const float*)d_in[6];
  const float* down_b = (const float*)d_in[7];
  const float* shg    = (const float*)d_in[8];
  const float* shu    = (const float*)d_in[9];
  const float* shd    = (const float*)d_in[10];
  float* out = (float*)d_out;

  const size_t H_BYTES  = (size_t)En * CAPn * Fn * 2;   // 134 MiB
  const size_t XB_BYTES = (size_t)Tn * Dn * 2;          // 16 MiB
  const size_t WE_BYTES = (size_t)En * Fn * Dn * 2;     // 128 MiB each
  const size_t SH_BYTES = (size_t)SHn * Dn * 2;         // 4 MiB each
  const size_t SC_BYTES = (size_t)En * Tn * 4;
  const size_t ID_BYTES = (size_t)En * CAPn * 4;
  const size_t need = H_BYTES + XB_BYTES + 3 * WE_BYTES + 3 * SH_BYTES +
                      SC_BYTES + 2 * ID_BYTES;
  if (ws_size < need) return;

  char* p = (char*)d_ws;
  unsigned short* H    = (unsigned short*)p; p += H_BYTES;
  unsigned short* xb   = (unsigned short*)p; p += XB_BYTES;
  unsigned short* upb  = (unsigned short*)p; p += WE_BYTES;
  unsigned short* gwb  = (unsigned short*)p; p += WE_BYTES;
  unsigned short* dwb  = (unsigned short*)p; p += WE_BYTES;
  unsigned short* shgb = (unsigned short*)p; p += SH_BYTES;
  unsigned short* shub = (unsigned short*)p; p += SH_BYTES;
  unsigned short* shdb = (unsigned short*)p; p += SH_BYTES;
  float* scores = (float*)p; p += SC_BYTES;
  int* ids      = (int*)p;  p += ID_BYTES;
  float* osc    = (float*)p;

  kcvt<<<2048, 256, 0, stream>>>(x, xb, Tn * Dn / 8);
  kscores<<<Tn, 256, 0, stream>>>(x, gate_w, scores);
  kselect<<<En, 256, 0, stream>>>(scores, ids, osc);
  kcvt<<<2048, 256, 0, stream>>>(up_w, upb, En * Fn * Dn / 8);
  kcvt<<<2048, 256, 0, stream>>>(gw, gwb, En * Fn * Dn / 8);
  kcvt<<<2048, 256, 0, stream>>>(down_w, dwb, En * Dn * Fn / 8);
  kcvt<<<256, 256, 0, stream>>>(shg, shgb, SHn * Dn / 8);
  kcvt<<<256, 256, 0, stream>>>(shu, shub, SHn * Dn / 8);
  kcvt<<<256, 256, 0, stream>>>(shd, shdb, Dn * SHn / 8);

  // shared GLU: M=Tn, N=SHn, K=Dn -> H[Tn][SHn]
  kgemm8<128, 2, false, 0><<<(Tn / 256) * (SHn / 128), 512, 0, stream>>>(
      xb, nullptr, shgb, shub, nullptr, nullptr, nullptr, H,
      SHn, Tn, Dn, Tn / 256, SHn / 128);
  // shared down: M=Tn, N=Dn, K=SHn -> out (dense store, covers all of d_out)
  kgemm8<128, 1, false, 1><<<(Tn / 256) * (Dn / 128), 512, 0, stream>>>(
      H, nullptr, shdb, nullptr, nullptr, nullptr, nullptr, out,
      Dn, Tn, SHn, Tn / 256, Dn / 128);
  // expert GLU: M=CAP (gathered), N=Fn, K=Dn, z=E -> H[E][CAP][Fn]
  kgemm8<128, 2, true, 0><<<(CAPn / 256) * (Fn / 128) * En, 512, 0, stream>>>(
      xb, ids, gwb, upb, gb, up_b, nullptr, H,
      Fn, CAPn, Dn, CAPn / 256, Fn / 128);
  // expert down: M=CAP, N=Dn, K=Fn, z=E -> scatter-add into out
  kgemm8<256, 1, false, 2><<<(CAPn / 256) * (Dn / 256) * En, 512, 0, stream>>>(
      H, ids, dwb, nullptr, down_b, nullptr, osc, out,
      Dn, CAPn, Fn, CAPn / 256, Dn / 256);
}

// Round 6
// 1136.415 us; speedup vs baseline: 1.0679x; 1.0679x over previous
//
#include <hip/hip_runtime.h>
#include <hip/hip_bf16.h>

#define Tn 8192
#define Dn 1024
#define Fn 4096
#define SHn 2048
#define En 16
#define CAPn 1024

typedef __bf16 bf16_t;
typedef bf16_t bf16x8 __attribute__((ext_vector_type(8)));
typedef float f32x4 __attribute__((ext_vector_type(4)));

__device__ __forceinline__ unsigned short f2bf(float f) {
  unsigned int u = __builtin_bit_cast(unsigned int, f);
  u += 0x7FFFu + ((u >> 16) & 1u);
  return (unsigned short)(u >> 16);
}
__device__ __forceinline__ unsigned int pack2(float a, float b) {
  return (unsigned int)f2bf(a) | ((unsigned int)f2bf(b) << 16);
}

__device__ __forceinline__ void gload16(const void* g, void* l) {
  __builtin_amdgcn_global_load_lds(
      (const __attribute__((address_space(1))) unsigned int*)g,
      (__attribute__((address_space(3))) unsigned int*)l, 16, 0, 0);
}

// ---------------- fp32 -> bf16 convert ----------------
__global__ __launch_bounds__(256) void kcvt(const float* __restrict__ s,
                                            unsigned short* __restrict__ d, int n8) {
  int i = blockIdx.x * 256 + threadIdx.x;
  int stride = gridDim.x * 256;
  const float4* sv = (const float4*)s;
  for (; i < n8; i += stride) {
    float4 a = sv[2 * i], b = sv[2 * i + 1];
    uint4 u = { pack2(a.x, a.y), pack2(a.z, a.w), pack2(b.x, b.y), pack2(b.z, b.w) };
    ((uint4*)d)[i] = u;
  }
}

// ---------------- gate scores: sigmoid(x @ gate_w^T), stored [E][T] ----------------
__global__ __launch_bounds__(256) void kscores(const float* __restrict__ x,
                                               const float* __restrict__ gw,
                                               float* __restrict__ sc) {
  __shared__ float sx[Dn];
  int tid = threadIdx.x, tok = blockIdx.x;
  ((float4*)sx)[tid] = ((const float4*)(x + (size_t)tok * Dn))[tid];
  __syncthreads();
  int e = tid >> 4, kl = tid & 15;
  const float4* w = (const float4*)(gw + e * Dn);
  const float4* xv = (const float4*)sx;
  float acc = 0.f;
#pragma unroll
  for (int j = 0; j < 16; ++j) {
    float4 a = w[kl + 16 * j], b = xv[kl + 16 * j];
    acc += a.x * b.x + a.y * b.y + a.z * b.z + a.w * b.w;
  }
#pragma unroll
  for (int off = 8; off; off >>= 1) acc += __shfl_xor(acc, off, 64);
  if (kl == 0) sc[(size_t)e * Tn + tok] = 1.f / (1.f + expf(-acc));
}

// ---------------- per-expert top-CAP radix select (ties: lowest index) ----------------
__global__ __launch_bounds__(256) void kselect(const float* __restrict__ scores,
                                               int* __restrict__ ids,
                                               float* __restrict__ oscore) {
  __shared__ unsigned int keys[Tn];
  __shared__ unsigned int hist[256];
  __shared__ unsigned int sh_prefix, sh_k, sh_cnt, sh_eq;
  __shared__ int eqlist[1024];
  const int tid = threadIdx.x, e = blockIdx.x;
  const float* row = scores + (size_t)e * Tn;
  for (int i = 0; i < Tn / 256; ++i)
    keys[tid + i * 256] = __float_as_uint(row[tid + i * 256]);
  if (tid == 0) { sh_prefix = 0u; sh_k = CAPn; }
  __syncthreads();
  for (int shift = 24; shift >= 0; shift -= 8) {
    hist[tid] = 0u;
    __syncthreads();
    unsigned int prefix = sh_prefix;
    unsigned int mask = (shift == 24) ? 0u : (0xFFFFFFFFu << (shift + 8));
    for (int i = 0; i < Tn / 256; ++i) {
      unsigned int kk = keys[tid + i * 256];
      if ((kk & mask) == prefix) atomicAdd(&hist[(kk >> shift) & 255], 1u);
    }
    __syncthreads();
    if (tid == 0) {
      unsigned int k = sh_k, c = 0; int b;
      for (b = 255; b >= 0; --b) { c += hist[b]; if (c >= k) break; }
      sh_k = k - (c - hist[b]);
      sh_prefix = prefix | ((unsigned int)b << shift);
    }
    __syncthreads();
  }
  const unsigned int thr = sh_prefix;
  if (tid == 0) { sh_cnt = 0u; sh_eq = 0u; }
  __syncthreads();
  const int base = e * CAPn;
  for (int i = 0; i < Tn / 256; ++i) {
    int t = tid + i * 256;
    unsigned int kk = keys[t];
    if (kk > thr) {
      unsigned int p = atomicAdd(&sh_cnt, 1u);
      ids[base + p] = t;
      oscore[base + p] = __uint_as_float(kk);
    } else if (kk == thr) {
      unsigned int p = atomicAdd(&sh_eq, 1u);
      if (p < 1024u) eqlist[p] = t;
    }
  }
  __syncthreads();
  if (tid == 0) {
    int need = CAPn - (int)sh_cnt;
    int m = (int)sh_eq; if (m > 1024) m = 1024;
    for (int j = 0; j < need; ++j) {
      int best = 1 << 30, bi = 0;
      for (int i2 = 0; i2 < m; ++i2)
        if (eqlist[i2] < best) { best = eqlist[i2]; bi = i2; }
      eqlist[bi] = 1 << 30;
      ids[base + (int)sh_cnt + j] = best;
      oscore[base + (int)sh_cnt + j] = __uint_as_float(thr);
    }
  }
}

// =====================================================================
// m201-style quadrant-phase GEMM. 512 threads, 8 waves (2M x 4N).
// BM=256, BK=64. Effective BN=256 (NOPS==1: one tensor, 256 cols;
// NOPS==2: two tensors Wg/Wu of 128 cols each -> C-quadrant n-half = tensor).
// LDS: 2 buffers x {A1,A2,B1,B2} halves of 16KB = 128KB.
// Phases per K-tile (gray-code quadrants): ph0{A1,B1} ph1{A1,B2}
// ph2{A2,B2} ph3{A2,B1}. Each phase stages ONE half-tile of t+1 then
// vmcnt(6): retires exactly the halves this phase reads (issued 4
// phases earlier = full K-tile of cover). Tail tile: vmcnt(4/2/0).
// EPI: 0 = GLU -> H bf16; 1 = dense fp32 store; 2 = scatter atomicAdd*score
// =====================================================================
#define READA(H)                                                              \
  _Pragma("unroll") for (int mf = 0; mf < 4; ++mf)                            \
  _Pragma("unroll") for (int kk = 0; kk < 2; ++kk)                            \
    av[mf][kk] = *(const bf16x8*)(cur + (H) * 16384u +                        \
        (unsigned)(wavem * 64 + mf * 16 + lrow) * 128u +                      \
        ((unsigned)((kk * 4 + lk) ^ (lrow & 7)) << 4));

#define READB(O)                                                              \
  _Pragma("unroll") for (int nf = 0; nf < 2; ++nf)                            \
  _Pragma("unroll") for (int kk = 0; kk < 2; ++kk)                            \
    bv[O][nf][kk] = *(const bf16x8*)(cur + 32768u + (O) * 16384u +            \
        (unsigned)(waven * 32 + nf * 16 + lrow) * 128u +                      \
        ((unsigned)((kk * 4 + lk) ^ (lrow & 7)) << 4));

#define MMACL(H, O)                                                           \
  _Pragma("unroll") for (int mf = 0; mf < 4; ++mf)                            \
  _Pragma("unroll") for (int nf = 0; nf < 2; ++nf)                            \
  _Pragma("unroll") for (int kk = 0; kk < 2; ++kk)                            \
    acc[H][O][mf][nf] = __builtin_amdgcn_mfma_f32_16x16x32_bf16(              \
        av[mf][kk], bv[O][nf][kk], acc[H][O][mf][nf], 0, 0, 0);

#define BARR __builtin_amdgcn_s_barrier()
#define SCHED __builtin_amdgcn_sched_barrier(0)
#define LGKM0 asm volatile("s_waitcnt lgkmcnt(0)" ::: "memory")

template <int NOPS, bool GATHER, int EPI>
__global__ __launch_bounds__(512, 2) void kgemm9(
    const unsigned short* __restrict__ Ab, const int* __restrict__ idsg,
    const unsigned short* __restrict__ B1b, const unsigned short* __restrict__ B2b,
    const float* __restrict__ bias1, const float* __restrict__ bias2,
    const float* __restrict__ scg, void* __restrict__ OutV,
    int N, int Mz, int K, int MBc, int NBc) {
  constexpr int BM = 256;
  __shared__ alignas(16) unsigned char lds[2][65536];
  __shared__ int sIds[BM];
  __shared__ float sSc[BM];

  const int tid = threadIdx.x;
  const int lane = tid & 63, w = tid >> 6;
  const int wavem = w >> 2, waven = w & 3;
  const int lrow = lane & 15, lk = lane >> 4;
  const int lr = lane >> 3, lc = lane & 7;
  const int srcb = ((lc ^ lr) << 4);

  const int nwg = gridDim.x;
  const int cpx = nwg >> 3;
  const int bid = blockIdx.x;
  const int swz = (bid & 7) * cpx + (bid >> 3);
  const int bm = swz % MBc;                      // bm fastest: weight-slab sharers adjacent
  const int bn = (swz / MBc) % NBc;
  const int z  = swz / (NBc * MBc);
  const int row0 = bm * BM;

  if (tid < BM) {
    if (GATHER || EPI == 2) {
      sIds[tid] = idsg[z * CAPn + row0 + tid];
      if (EPI == 2) sSc[tid] = scg[z * CAPn + row0 + tid];
    }
  }
  __syncthreads();

  const size_t ks = (size_t)K * 2;  // row stride in bytes
  const unsigned char* Az = (const unsigned char*)Ab + (EPI == 2 ? (size_t)z * Mz * ks : 0);
  const unsigned char* B1z = (const unsigned char*)B1b + (size_t)z * N * ks;
  const unsigned char* B2z = (NOPS == 2) ? (const unsigned char*)B2b + (size_t)z * N * ks : nullptr;

  // stage source pointers: issue i covers half (i>>1), local rows (i&1)*64 + w*8 + lr
  const unsigned char* aR[4];
#pragma unroll
  for (int i = 0; i < 4; ++i) {
    int rr = i * 64 + w * 8 + lr;  // global tile row = half*(128) + local
    size_t arow = GATHER ? (size_t)sIds[rr] : (size_t)(row0 + rr);
    aR[i] = Az + arow * ks + srcb;
  }
  const unsigned char* bR[2][2];
#pragma unroll
  for (int o = 0; o < 2; ++o)
#pragma unroll
    for (int j = 0; j < 2; ++j) {
      if (NOPS == 2) {
        int rr = bn * 128 + j * 64 + w * 8 + lr;
        bR[o][j] = (o ? B2z : B1z) + (size_t)rr * ks + srcb;
      } else {
        int rr = bn * 256 + o * 128 + j * 64 + w * 8 + lr;
        bR[o][j] = B1z + (size_t)rr * ks + srcb;
      }
    }

  auto stgA = [&](int i, unsigned char* buf, int kb) {
    gload16(aR[i] + kb, buf + (unsigned)(i >> 1) * 16384u + (unsigned)(i & 1) * 8192u + (unsigned)w * 1024u);
  };
  auto stgB = [&](int o, int j, unsigned char* buf, int kb) {
    gload16(bR[o][j] + kb, buf + 32768u + (unsigned)o * 16384u + (unsigned)j * 8192u + (unsigned)w * 1024u);
  };

  f32x4 acc[2][2][4][2];
#pragma unroll
  for (int h = 0; h < 2; ++h)
#pragma unroll
    for (int o = 0; o < 2; ++o)
#pragma unroll
      for (int mf = 0; mf < 4; ++mf)
#pragma unroll
        for (int nf = 0; nf < 2; ++nf) acc[h][o][mf][nf] = {0.f, 0.f, 0.f, 0.f};

  bf16x8 av[4][2], bv[2][2][2];

  // prologue: stage tile 0 in need-order A1, B1, B2, A2 (8 loads, no wait)
  stgA(0, lds[0], 0); stgA(1, lds[0], 0);
  stgB(0, 0, lds[0], 0); stgB(0, 1, lds[0], 0);
  stgB(1, 0, lds[0], 0); stgB(1, 1, lds[0], 0);
  stgA(2, lds[0], 0); stgA(3, lds[0], 0);

  const int NT = K >> 6;
  for (int t = 0; t < NT; ++t) {
    unsigned char* cur = &lds[t & 1][0];
    unsigned char* nxt = &lds[(t + 1) & 1][0];
    const bool pre = (t + 1 < NT);
    const int kb = (t + 1) * 128;

    // ---- ph0: quadrant (A1,B1) ----
    if (pre) { stgA(0, nxt, kb); stgA(1, nxt, kb); }
    if (pre) asm volatile("s_waitcnt vmcnt(6)" ::: "memory");
    else     asm volatile("s_waitcnt vmcnt(4)" ::: "memory");
    BARR;
    READA(0); READB(0);
    LGKM0; SCHED;
    __builtin_amdgcn_s_setprio(1);
    MMACL(0, 0);
    __builtin_amdgcn_s_setprio(0);
    SCHED; BARR;

    // ---- ph1: quadrant (A1,B2) ----
    if (pre) { stgB(0, 0, nxt, kb); stgB(0, 1, nxt, kb); }
    if (pre) asm volatile("s_waitcnt vmcnt(6)" ::: "memory");
    else     asm volatile("s_waitcnt vmcnt(2)" ::: "memory");
    BARR;
    READB(1);
    LGKM0; SCHED;
    __builtin_amdgcn_s_setprio(1);
    MMACL(0, 1);
    __builtin_amdgcn_s_setprio(0);
    SCHED; BARR;

    // ---- ph2: quadrant (A2,B2) ----
    if (pre) { stgB(1, 0, nxt, kb); stgB(1, 1, nxt, kb); }
    if (pre) asm volatile("s_waitcnt vmcnt(6)" ::: "memory");
    else     asm volatile("s_waitcnt vmcnt(0)" ::: "memory");
    BARR;
    READA(1);
    LGKM0; SCHED;
    __builtin_amdgcn_s_setprio(1);
    MMACL(1, 1);
    __builtin_amdgcn_s_setprio(0);
    SCHED; BARR;

    // ---- ph3: quadrant (A2,B1) — all operands already in registers ----
    if (pre) { stgA(2, nxt, kb); stgA(3, nxt, kb); }
    BARR;
    __builtin_amdgcn_s_setprio(1);
    MMACL(1, 0);
    __builtin_amdgcn_s_setprio(0);
    SCHED; BARR;
  }

  // ---------------- epilogue ----------------
  if (EPI == 0) {
    unsigned short* H = (unsigned short*)OutV;
#pragma unroll
    for (int nf = 0; nf < 2; ++nf) {
      int col = bn * 128 + waven * 32 + nf * 16 + lrow;
      float bg = bias1 ? bias1[(size_t)z * N + col] : 0.f;
      float bu = bias2 ? bias2[(size_t)z * N + col] : 0.f;
#pragma unroll
      for (int h = 0; h < 2; ++h)
#pragma unroll
        for (int mf = 0; mf < 4; ++mf)
#pragma unroll
          for (int j = 0; j < 4; ++j) {
            float g = acc[h][0][mf][nf][j] + bg;
            float u = acc[h][1][mf][nf][j] + bu;
            float hv = g / (1.f + __expf(-g)) * u;
            int row = row0 + h * 128 + wavem * 64 + mf * 16 + lk * 4 + j;
            H[(size_t)z * Mz * N + (size_t)row * N + col] = f2bf(hv);
          }
    }
  } else {
    float* Out = (float*)OutV;
#pragma unroll
    for (int o = 0; o < 2; ++o)
#pragma unroll
      for (int nf = 0; nf < 2; ++nf) {
        int col = bn * 256 + o * 128 + waven * 32 + nf * 16 + lrow;
        float bb = bias1 ? bias1[(size_t)z * N + col] : 0.f;
#pragma unroll
        for (int h = 0; h < 2; ++h)
#pragma unroll
          for (int mf = 0; mf < 4; ++mf)
#pragma unroll
            for (int j = 0; j < 4; ++j) {
              int rl = h * 128 + wavem * 64 + mf * 16 + lk * 4 + j;
              float v = acc[h][o][mf][nf][j] + bb;
              if (EPI == 2) {
                atomicAdd(Out + (size_t)sIds[rl] * Dn + col, sSc[rl] * v);
              } else {
                Out[(size_t)(row0 + rl) * Dn + col] = v;
              }
            }
      }
  }
}

extern "C" void kernel_launch(void* const* d_in, const int* in_sizes, int n_in,
                              void* d_out, int out_size, void* d_ws, size_t ws_size,
                              hipStream_t stream) {
  const float* x      = (const float*)d_in[0];
  const float* gate_w = (const float*)d_in[1];
  const float* up_w   = (const float*)d_in[2];
  const float* up_b   = (const float*)d_in[3];
  const float* gw     = (const float*)d_in[4];
  const float* gb     = (const float*)d_in[5];
  const float* down_w = (const float*)d_in[6];
  const float* down_b = (const float*)d_in[7];
  const float* shg    = (const float*)d_in[8];
  const float* shu    = (const float*)d_in[9];
  const float* shd    = (const float*)d_in[10];
  float* out = (float*)d_out;

  const size_t H_BYTES  = (size_t)En * CAPn * Fn * 2;   // 134 MiB
  const size_t XB_BYTES = (size_t)Tn * Dn * 2;          // 16 MiB
  const size_t WE_BYTES = (size_t)En * Fn * Dn * 2;     // 128 MiB each
  const size_t SH_BYTES = (size_t)SHn * Dn * 2;         // 4 MiB each
  const size_t SC_BYTES = (size_t)En * Tn * 4;
  const size_t ID_BYTES = (size_t)En * CAPn * 4;
  const size_t need = H_BYTES + XB_BYTES + 3 * WE_BYTES + 3 * SH_BYTES +
                      SC_BYTES + 2 * ID_BYTES;
  if (ws_size < need) return;

  char* p = (char*)d_ws;
  unsigned short* H    = (unsigned short*)p; p += H_BYTES;
  unsigned short* xb   = (unsigned short*)p; p += XB_BYTES;
  unsigned short* upb  = (unsigned short*)p; p += WE_BYTES;
  unsigned short* gwb  = (unsigned short*)p; p += WE_BYTES;
  unsigned short* dwb  = (unsigned short*)p; p += WE_BYTES;
  unsigned short* shgb = (unsigned short*)p; p += SH_BYTES;
  unsigned short* shub = (unsigned short*)p; p += SH_BYTES;
  unsigned short* shdb = (unsigned short*)p; p += SH_BYTES;
  float* scores = (float*)p; p += SC_BYTES;
  int* ids      = (int*)p;  p += ID_BYTES;
  float* osc    = (float*)p;

  kcvt<<<2048, 256, 0, stream>>>(x, xb, Tn * Dn / 8);
  kscores<<<Tn, 256, 0, stream>>>(x, gate_w, scores);
  kselect<<<En, 256, 0, stream>>>(scores, ids, osc);
  kcvt<<<2048, 256, 0, stream>>>(up_w, upb, En * Fn * Dn / 8);
  kcvt<<<2048, 256, 0, stream>>>(gw, gwb, En * Fn * Dn / 8);
  kcvt<<<2048, 256, 0, stream>>>(down_w, dwb, En * Dn * Fn / 8);
  kcvt<<<256, 256, 0, stream>>>(shg, shgb, SHn * Dn / 8);
  kcvt<<<256, 256, 0, stream>>>(shu, shub, SHn * Dn / 8);
  kcvt<<<256, 256, 0, stream>>>(shd, shdb, Dn * SHn / 8);

  // shared GLU: M=Tn, N=SHn, K=Dn -> H[Tn][SHn]
  kgemm9<2, false, 0><<<(Tn / 256) * (SHn / 128), 512, 0, stream>>>(
      xb, nullptr, shgb, shub, nullptr, nullptr, nullptr, H,
      SHn, Tn, Dn, Tn / 256, SHn / 128);
  // shared down: M=Tn, N=Dn, K=SHn -> out (dense store, covers all of d_out)
  kgemm9<1, false, 1><<<(Tn / 256) * (Dn / 256), 512, 0, stream>>>(
      H, nullptr, shdb, nullptr, nullptr, nullptr, nullptr, out,
      Dn, Tn, SHn, Tn / 256, Dn / 256);
  // expert GLU: M=CAP (gathered), N=Fn, K=Dn, z=E -> H[E][CAP][Fn]
  kgemm9<2, true, 0><<<(CAPn / 256) * (Fn / 128) * En, 512, 0, stream>>>(
      xb, ids, gwb, upb, gb, up_b, nullptr, H,
      Fn, CAPn, Dn, CAPn / 256, Fn / 128);
  // expert down: M=CAP, N=Dn, K=Fn, z=E -> scatter-add into out
  kgemm9<1, false, 2><<<(CAPn / 256) * (Dn / 256) * En, 512, 0, stream>>>(
      H, ids, dwb, nullptr, down_b, nullptr, osc, out,
      Dn, CAPn, Fn, CAPn / 256, Dn / 256);
}

// Round 7
// 997.312 us; speedup vs baseline: 1.2168x; 1.1395x over previous
//
#include <hip/hip_runtime.h>
#include <hip/hip_bf16.h>

#define Tn 8192
#define Dn 1024
#define Fn 4096
#define SHn 2048
#define En 16
#define CAPn 1024

typedef __bf16 bf16_t;
typedef bf16_t bf16x8 __attribute__((ext_vector_type(8)));
typedef float f32x4 __attribute__((ext_vector_type(4)));
typedef float f32x16 __attribute__((ext_vector_type(16)));

__device__ __forceinline__ unsigned short f2bf(float f) {
  unsigned int u = __builtin_bit_cast(unsigned int, f);
  u += 0x7FFFu + ((u >> 16) & 1u);
  return (unsigned short)(u >> 16);
}
__device__ __forceinline__ unsigned int pack2(float a, float b) {
  return (unsigned int)f2bf(a) | ((unsigned int)f2bf(b) << 16);
}

__device__ __forceinline__ void gload16(const void* g, void* l) {
  __builtin_amdgcn_global_load_lds(
      (const __attribute__((address_space(1))) unsigned int*)g,
      (__attribute__((address_space(3))) unsigned int*)l, 16, 0, 0);
}

// ---------------- fp32 -> bf16 convert ----------------
__global__ __launch_bounds__(256) void kcvt(const float* __restrict__ s,
                                            unsigned short* __restrict__ d, int n8) {
  int i = blockIdx.x * 256 + threadIdx.x;
  int stride = gridDim.x * 256;
  const float4* sv = (const float4*)s;
  for (; i < n8; i += stride) {
    float4 a = sv[2 * i], b = sv[2 * i + 1];
    uint4 u = { pack2(a.x, a.y), pack2(a.z, a.w), pack2(b.x, b.y), pack2(b.z, b.w) };
    ((uint4*)d)[i] = u;
  }
}

// ---------------- gate scores: sigmoid(x @ gate_w^T), stored [E][T] ----------------
__global__ __launch_bounds__(256) void kscores(const float* __restrict__ x,
                                               const float* __restrict__ gw,
                                               float* __restrict__ sc) {
  __shared__ float sx[Dn];
  int tid = threadIdx.x, tok = blockIdx.x;
  ((float4*)sx)[tid] = ((const float4*)(x + (size_t)tok * Dn))[tid];
  __syncthreads();
  int e = tid >> 4, kl = tid & 15;
  const float4* w = (const float4*)(gw + e * Dn);
  const float4* xv = (const float4*)sx;
  float acc = 0.f;
#pragma unroll
  for (int j = 0; j < 16; ++j) {
    float4 a = w[kl + 16 * j], b = xv[kl + 16 * j];
    acc += a.x * b.x + a.y * b.y + a.z * b.z + a.w * b.w;
  }
#pragma unroll
  for (int off = 8; off; off >>= 1) acc += __shfl_xor(acc, off, 64);
  if (kl == 0) sc[(size_t)e * Tn + tok] = 1.f / (1.f + expf(-acc));
}

// ---------------- per-expert top-CAP radix select (ties: lowest index) ----------------
__global__ __launch_bounds__(256) void kselect(const float* __restrict__ scores,
                                               int* __restrict__ ids,
                                               float* __restrict__ oscore) {
  __shared__ unsigned int keys[Tn];
  __shared__ unsigned int hist[256];
  __shared__ unsigned int sh_prefix, sh_k, sh_cnt, sh_eq;
  __shared__ int eqlist[1024];
  const int tid = threadIdx.x, e = blockIdx.x;
  const float* row = scores + (size_t)e * Tn;
  for (int i = 0; i < Tn / 256; ++i)
    keys[tid + i * 256] = __float_as_uint(row[tid + i * 256]);
  if (tid == 0) { sh_prefix = 0u; sh_k = CAPn; }
  __syncthreads();
  for (int shift = 24; shift >= 0; shift -= 8) {
    hist[tid] = 0u;
    __syncthreads();
    unsigned int prefix = sh_prefix;
    unsigned int mask = (shift == 24) ? 0u : (0xFFFFFFFFu << (shift + 8));
    for (int i = 0; i < Tn / 256; ++i) {
      unsigned int kk = keys[tid + i * 256];
      if ((kk & mask) == prefix) atomicAdd(&hist[(kk >> shift) & 255], 1u);
    }
    __syncthreads();
    if (tid == 0) {
      unsigned int k = sh_k, c = 0; int b;
      for (b = 255; b >= 0; --b) { c += hist[b]; if (c >= k) break; }
      sh_k = k - (c - hist[b]);
      sh_prefix = prefix | ((unsigned int)b << shift);
    }
    __syncthreads();
  }
  const unsigned int thr = sh_prefix;
  if (tid == 0) { sh_cnt = 0u; sh_eq = 0u; }
  __syncthreads();
  const int base = e * CAPn;
  for (int i = 0; i < Tn / 256; ++i) {
    int t = tid + i * 256;
    unsigned int kk = keys[t];
    if (kk > thr) {
      unsigned int p = atomicAdd(&sh_cnt, 1u);
      ids[base + p] = t;
      oscore[base + p] = __uint_as_float(kk);
    } else if (kk == thr) {
      unsigned int p = atomicAdd(&sh_eq, 1u);
      if (p < 1024u) eqlist[p] = t;
    }
  }
  __syncthreads();
  if (tid == 0) {
    int need = CAPn - (int)sh_cnt;
    int m = (int)sh_eq; if (m > 1024) m = 1024;
    for (int j = 0; j < need; ++j) {
      int best = 1 << 30, bi = 0;
      for (int i2 = 0; i2 < m; ++i2)
        if (eqlist[i2] < best) { best = eqlist[i2]; bi = i2; }
      eqlist[bi] = 1 << 30;
      ids[base + (int)sh_cnt + j] = best;
      oscore[base + (int)sh_cnt + j] = __uint_as_float(thr);
    }
  }
}

// =====================================================================
// Round-2 structure (2-phase, 128x128 tiles, 48KB LDS -> 2 blocks/CU,
// global_load_lds + both-sides XOR swizzle, bm-fastest + XCD chunk
// swizzle) with 32x32x16 MFMA (half the MFMA instructions per FLOP).
// A/B frag: lane l holds [row=l&31][k=(l>>5)*8+j], 16B contiguous.
// C/D frag: col=lane&31, row=(reg&3)+8*(reg>>2)+4*(lane>>5).
// =====================================================================

// GLU: H = bf16( silu(A@Wg^T + bg) * (A@Wu^T + bu) ), K = Dn
template <bool GATHER>
__global__ __launch_bounds__(256, 2) void kglu_bf(
    const unsigned short* __restrict__ X, const int* __restrict__ idsg,
    const unsigned short* __restrict__ Wg, const unsigned short* __restrict__ Wu,
    const float* __restrict__ biasg, const float* __restrict__ biasu,
    unsigned short* __restrict__ H, int N, int Mz, int MB, int NB) {
  constexpr int K = Dn;
  __shared__ alignas(16) unsigned char sA[16384];
  __shared__ alignas(16) unsigned char sB1[16384];
  __shared__ alignas(16) unsigned char sB2[16384];
  __shared__ int sIds[128];
  const int tid = threadIdx.x;
  const int nwg = gridDim.x;
  const int cpx = nwg >> 3;
  const int bid = blockIdx.x;
  const int swz = (bid & 7) * cpx + (bid >> 3);
  const int bm = swz % MB;
  const int bn = (swz / MB) % NB;
  const int z  = swz / (MB * NB);
  const int lane = tid & 63, w = tid >> 6;
  const int wm = w >> 1, wn = w & 1;
  const int row32 = lane & 31, kh = lane >> 5;
  const int row0 = bm * 128;

  if (tid < 128) sIds[tid] = GATHER ? idsg[z * CAPn + row0 + tid] : (row0 + tid);
  __syncthreads();

  // per-lane staging source addresses (pre-swizzled chunk so LDS ends up XOR-swizzled)
  const int lr = lane >> 3;                 // row within an 8-row issue
  const int lc = lane & 7;                  // linear LDS chunk slot this lane fills
  const int srcb = ((lc ^ lr) << 4);        // source byte offset within the 128B row
  const unsigned char* Xb = (const unsigned char*)X;
  const unsigned char* Gb = (const unsigned char*)Wg + (size_t)z * N * (K * 2);
  const unsigned char* Ub = (const unsigned char*)Wu + (size_t)z * N * (K * 2);
  const unsigned char* aP[4];
#pragma unroll
  for (int i = 0; i < 4; ++i) {
    int ar = w * 32 + 8 * i + lr;
    aP[i] = Xb + (size_t)sIds[ar] * (K * 2) + srcb;
  }
  const int br0 = bn * 128 + w * 32 + lr;
  const unsigned char* gP0 = Gb + (size_t)br0 * (K * 2) + srcb;
  const unsigned char* uP0 = Ub + (size_t)br0 * (K * 2) + srcb;

  f32x16 accG[2][2], accU[2][2];
#pragma unroll
  for (int m = 0; m < 2; ++m)
#pragma unroll
    for (int n = 0; n < 2; ++n) {
      accG[m][n] = (f32x16)(0.f);
      accU[m][n] = (f32x16)(0.f);
    }

  for (int k0b = 0; k0b < K * 2; k0b += 128) {
    __syncthreads();
#pragma unroll
    for (int i = 0; i < 4; ++i) {
      unsigned ldsoff = (unsigned)(w * 32 + 8 * i) * 128u;
      gload16(aP[i] + k0b, sA + ldsoff);
      gload16(gP0 + (size_t)i * 8 * (K * 2) + k0b, sB1 + ldsoff);
      gload16(uP0 + (size_t)i * 8 * (K * 2) + k0b, sB2 + ldsoff);
    }
    __syncthreads();
#pragma unroll
    for (int ks = 0; ks < 4; ++ks) {
      const int swb = (((ks * 2 + kh) ^ (row32 & 7)) << 4);
      bf16x8 av[2], gv[2], uv[2];
#pragma unroll
      for (int m = 0; m < 2; ++m)
        av[m] = *(const bf16x8*)(sA + (wm * 64 + m * 32 + row32) * 128 + swb);
#pragma unroll
      for (int n = 0; n < 2; ++n) {
        gv[n] = *(const bf16x8*)(sB1 + (wn * 64 + n * 32 + row32) * 128 + swb);
        uv[n] = *(const bf16x8*)(sB2 + (wn * 64 + n * 32 + row32) * 128 + swb);
      }
#pragma unroll
      for (int m = 0; m < 2; ++m)
#pragma unroll
        for (int n = 0; n < 2; ++n) {
          accG[m][n] = __builtin_amdgcn_mfma_f32_32x32x16_bf16(av[m], gv[n], accG[m][n], 0, 0, 0);
          accU[m][n] = __builtin_amdgcn_mfma_f32_32x32x16_bf16(av[m], uv[n], accU[m][n], 0, 0, 0);
        }
    }
  }
#pragma unroll
  for (int n = 0; n < 2; ++n) {
    int col = bn * 128 + wn * 64 + n * 32 + row32;
    float bg = biasg ? biasg[(size_t)z * N + col] : 0.f;
    float bu = biasu ? biasu[(size_t)z * N + col] : 0.f;
#pragma unroll
    for (int m = 0; m < 2; ++m) {
#pragma unroll
      for (int reg = 0; reg < 16; ++reg) {
        float g = accG[m][n][reg] + bg;
        float u = accU[m][n][reg] + bu;
        float h = g / (1.f + __expf(-g)) * u;
        int row = row0 + wm * 64 + m * 32 + (reg & 3) + 8 * (reg >> 2) + 4 * kh;
        H[(size_t)z * Mz * N + (size_t)row * N + col] = f2bf(h);
      }
    }
  }
}

// down: Out = A@W^T (+bias, xscore scatter-add when SCATTER), N = Dn
template <int K, bool SCATTER>
__global__ __launch_bounds__(256, 2) void kdown_bf(
    const unsigned short* __restrict__ Hin, const unsigned short* __restrict__ W,
    const float* __restrict__ bias, const int* __restrict__ idsg,
    const float* __restrict__ scg, float* __restrict__ Out, int Mz, int MB, int NB) {
  constexpr int N = Dn;
  __shared__ alignas(16) unsigned char sA[16384];
  __shared__ alignas(16) unsigned char sB[16384];
  __shared__ int sIds[128];
  __shared__ float sSc[128];
  const int tid = threadIdx.x;
  const int nwg = gridDim.x;
  const int cpx = nwg >> 3;
  const int bid = blockIdx.x;
  const int swz = (bid & 7) * cpx + (bid >> 3);
  const int bm = swz % MB;
  const int bn = (swz / MB) % NB;
  const int z  = swz / (MB * NB);
  const int lane = tid & 63, w = tid >> 6;
  const int wm = w >> 1, wn = w & 1;
  const int row32 = lane & 31, kh = lane >> 5;
  const int row0 = bm * 128;

  if (SCATTER && tid < 128) {
    sIds[tid] = idsg[z * CAPn + row0 + tid];
    sSc[tid] = scg[z * CAPn + row0 + tid];
  }
  __syncthreads();

  const int lr = lane >> 3;
  const int lc = lane & 7;
  const int srcb = ((lc ^ lr) << 4);
  const unsigned char* Ab = (const unsigned char*)Hin + (size_t)z * Mz * (K * 2);
  const unsigned char* Wb = (const unsigned char*)W + (size_t)z * N * (K * 2);
  const int ar0 = row0 + w * 32 + lr;
  const int br0 = bn * 128 + w * 32 + lr;
  const unsigned char* aP0 = Ab + (size_t)ar0 * (K * 2) + srcb;
  const unsigned char* bP0 = Wb + (size_t)br0 * (K * 2) + srcb;

  f32x16 acc[2][2];
#pragma unroll
  for (int m = 0; m < 2; ++m)
#pragma unroll
    for (int n = 0; n < 2; ++n) acc[m][n] = (f32x16)(0.f);

  for (int k0b = 0; k0b < K * 2; k0b += 128) {
    __syncthreads();
#pragma unroll
    for (int i = 0; i < 4; ++i) {
      unsigned ldsoff = (unsigned)(w * 32 + 8 * i) * 128u;
      gload16(aP0 + (size_t)i * 8 * (K * 2) + k0b, sA + ldsoff);
      gload16(bP0 + (size_t)i * 8 * (K * 2) + k0b, sB + ldsoff);
    }
    __syncthreads();
#pragma unroll
    for (int ks = 0; ks < 4; ++ks) {
      const int swb = (((ks * 2 + kh) ^ (row32 & 7)) << 4);
      bf16x8 av[2], bv[2];
#pragma unroll
      for (int m = 0; m < 2; ++m)
        av[m] = *(const bf16x8*)(sA + (wm * 64 + m * 32 + row32) * 128 + swb);
#pragma unroll
      for (int n = 0; n < 2; ++n)
        bv[n] = *(const bf16x8*)(sB + (wn * 64 + n * 32 + row32) * 128 + swb);
#pragma unroll
      for (int m = 0; m < 2; ++m)
#pragma unroll
        for (int n = 0; n < 2; ++n)
          acc[m][n] = __builtin_amdgcn_mfma_f32_32x32x16_bf16(av[m], bv[n], acc[m][n], 0, 0, 0);
    }
  }
#pragma unroll
  for (int n = 0; n < 2; ++n) {
    int col = bn * 128 + wn * 64 + n * 32 + row32;
    float bvv = bias ? bias[(size_t)z * N + col] : 0.f;
#pragma unroll
    for (int m = 0; m < 2; ++m) {
#pragma unroll
      for (int reg = 0; reg < 16; ++reg) {
        int rl = wm * 64 + m * 32 + (reg & 3) + 8 * (reg >> 2) + 4 * kh;
        float v = acc[m][n][reg] + bvv;
        if (SCATTER) {
          atomicAdd(Out + (size_t)sIds[rl] * Dn + col, sSc[rl] * v);
        } else {
          Out[(size_t)(row0 + rl) * Dn + col] = v;
        }
      }
    }
  }
}

extern "C" void kernel_launch(void* const* d_in, const int* in_sizes, int n_in,
                              void* d_out, int out_size, void* d_ws, size_t ws_size,
                              hipStream_t stream) {
  const float* x      = (const float*)d_in[0];
  const float* gate_w = (const float*)d_in[1];
  const float* up_w   = (const float*)d_in[2];
  const float* up_b   = (const float*)d_in[3];
  const float* gw     = (const float*)d_in[4];
  const float* gb     = (const float*)d_in[5];
  const float* down_w = (const float*)d_in[6];
  const float* down_b = (const float*)d_in[7];
  const float* shg    = (const float*)d_in[8];
  const float* shu    = (const float*)d_in[9];
  const float* shd    = (const float*)d_in[10];
  float* out = (float*)d_out;

  const size_t H_BYTES  = (size_t)En * CAPn * Fn * 2;   // 134 MiB
  const size_t XB_BYTES = (size_t)Tn * Dn * 2;          // 16 MiB
  const size_t WE_BYTES = (size_t)En * Fn * Dn * 2;     // 128 MiB each
  const size_t SH_BYTES = (size_t)SHn * Dn * 2;         // 4 MiB each
  const size_t SC_BYTES = (size_t)En * Tn * 4;
  const size_t ID_BYTES = (size_t)En * CAPn * 4;
  const size_t need = H_BYTES + XB_BYTES + 3 * WE_BYTES + 3 * SH_BYTES +
                      SC_BYTES + 2 * ID_BYTES;
  if (ws_size < need) return;

  char* p = (char*)d_ws;
  unsigned short* H    = (unsigned short*)p; p += H_BYTES;
  unsigned short* xb   = (unsigned short*)p; p += XB_BYTES;
  unsigned short* upb  = (unsigned short*)p; p += WE_BYTES;
  unsigned short* gwb  = (unsigned short*)p; p += WE_BYTES;
  unsigned short* dwb  = (unsigned short*)p; p += WE_BYTES;
  unsigned short* shgb = (unsigned short*)p; p += SH_BYTES;
  unsigned short* shub = (unsigned short*)p; p += SH_BYTES;
  unsigned short* shdb = (unsigned short*)p; p += SH_BYTES;
  float* scores = (float*)p; p += SC_BYTES;
  int* ids      = (int*)p;  p += ID_BYTES;
  float* osc    = (float*)p;

  kcvt<<<2048, 256, 0, stream>>>(x, xb, Tn * Dn / 8);
  kscores<<<Tn, 256, 0, stream>>>(x, gate_w, scores);
  kselect<<<En, 256, 0, stream>>>(scores, ids, osc);
  kcvt<<<2048, 256, 0, stream>>>(up_w, upb, En * Fn * Dn / 8);
  kcvt<<<2048, 256, 0, stream>>>(gw, gwb, En * Fn * Dn / 8);
  kcvt<<<2048, 256, 0, stream>>>(down_w, dwb, En * Dn * Fn / 8);
  kcvt<<<256, 256, 0, stream>>>(shg, shgb, SHn * Dn / 8);
  kcvt<<<256, 256, 0, stream>>>(shu, shub, SHn * Dn / 8);
  kcvt<<<256, 256, 0, stream>>>(shd, shdb, Dn * SHn / 8);

  // shared dense GLU MLP (writes every element of d_out)
  kglu_bf<false><<<(Tn / 128) * (SHn / 128), 256, 0, stream>>>(
      xb, nullptr, shgb, shub, nullptr, nullptr, H, SHn, Tn, Tn / 128, SHn / 128);
  kdown_bf<SHn, false><<<(Tn / 128) * (Dn / 128), 256, 0, stream>>>(
      H, shdb, nullptr, nullptr, nullptr, out, Tn, Tn / 128, Dn / 128);

  // expert path (atomic scatter-add on top)
  kglu_bf<true><<<(CAPn / 128) * (Fn / 128) * En, 256, 0, stream>>>(
      xb, ids, gwb, upb, gb, up_b, H, Fn, CAPn, CAPn / 128, Fn / 128);
  kdown_bf<Fn, true><<<(CAPn / 128) * (Dn / 128) * En, 256, 0, stream>>>(
      H, dwb, down_b, ids, osc, out, CAPn, CAPn / 128, Dn / 128);
}

// Round 8
// 967.317 us; speedup vs baseline: 1.2546x; 1.0310x over previous
//
#include <hip/hip_runtime.h>
#include <hip/hip_bf16.h>

#define Tn 8192
#define Dn 1024
#define Fn 4096
#define SHn 2048
#define En 16
#define CAPn 1024

typedef __bf16 bf16_t;
typedef bf16_t bf16x8 __attribute__((ext_vector_type(8)));
typedef float f32x4 __attribute__((ext_vector_type(4)));

__device__ __forceinline__ unsigned short f2bf(float f) {
  unsigned int u = __builtin_bit_cast(unsigned int, f);
  u += 0x7FFFu + ((u >> 16) & 1u);
  return (unsigned short)(u >> 16);
}
__device__ __forceinline__ unsigned int pack2(float a, float b) {
  return (unsigned int)f2bf(a) | ((unsigned int)f2bf(b) << 16);
}

__device__ __forceinline__ void gload16(const void* g, void* l) {
  __builtin_amdgcn_global_load_lds(
      (const __attribute__((address_space(1))) unsigned int*)g,
      (__attribute__((address_space(3))) unsigned int*)l, 16, 0, 0);
}

// grid-stride fp32->bf16 over up to two tensors (used by fused conv blocks)
__device__ __forceinline__ void conv_blocks(int cb, int ncb, int tid,
                                            const float* s1, unsigned short* d1, int n1,
                                            const float* s2, unsigned short* d2, int n2) {
  const int tot = n1 + n2;
  for (int i = cb * 256 + tid; i < tot; i += ncb * 256) {
    const float4* sv; uint4* dv; int j;
    if (i < n1) { j = i; sv = (const float4*)s1; dv = (uint4*)d1; }
    else        { j = i - n1; sv = (const float4*)s2; dv = (uint4*)d2; }
    float4 a = sv[2 * j], b = sv[2 * j + 1];
    dv[j] = uint4{ pack2(a.x, a.y), pack2(a.z, a.w), pack2(b.x, b.y), pack2(b.z, b.w) };
  }
}

// ---------------- gate scores + x->bf16 + shared-weight converts ----------------
// blocks [0,Tn): one token each -> scores[E][tok] and xb row.
// blocks [Tn, Tn+NCONV): grid-stride convert of shg/shu/shd.
__global__ __launch_bounds__(256) void kscores_cvt(
    const float* __restrict__ x, const float* __restrict__ gw,
    float* __restrict__ sc, unsigned short* __restrict__ xb,
    const float* __restrict__ shg, unsigned short* __restrict__ shgb,
    const float* __restrict__ shu, unsigned short* __restrict__ shub,
    const float* __restrict__ shd, unsigned short* __restrict__ shdb) {
  __shared__ float sx[Dn];
  const int tid = threadIdx.x;
  if (blockIdx.x >= Tn) {
    const int cb = blockIdx.x - Tn, ncb = gridDim.x - Tn;
    constexpr int nsh = SHn * Dn / 8;  // per tensor (all three same size)
    conv_blocks(cb, ncb, tid, shg, shgb, nsh, shu, shub, nsh);
    conv_blocks(cb, ncb, tid, shd, shdb, nsh, nullptr, nullptr, 0);
    return;
  }
  const int tok = blockIdx.x;
  float4 v = ((const float4*)(x + (size_t)tok * Dn))[tid];
  ((float4*)sx)[tid] = v;
  ((uint2*)(xb + (size_t)tok * Dn))[tid] = uint2{ pack2(v.x, v.y), pack2(v.z, v.w) };
  __syncthreads();
  int e = tid >> 4, kl = tid & 15;
  const float4* w = (const float4*)(gw + e * Dn);
  const float4* xv = (const float4*)sx;
  float acc = 0.f;
#pragma unroll
  for (int j = 0; j < 16; ++j) {
    float4 a = w[kl + 16 * j], b = xv[kl + 16 * j];
    acc += a.x * b.x + a.y * b.y + a.z * b.z + a.w * b.w;
  }
#pragma unroll
  for (int off = 8; off; off >>= 1) acc += __shfl_xor(acc, off, 64);
  if (kl == 0) sc[(size_t)e * Tn + tok] = 1.f / (1.f + expf(-acc));
}

// ---------------- per-expert top-CAP radix select (ties: lowest index) ----------------
__global__ __launch_bounds__(256) void kselect(const float* __restrict__ scores,
                                               int* __restrict__ ids,
                                               float* __restrict__ oscore) {
  __shared__ unsigned int keys[Tn];
  __shared__ unsigned int hist[256];
  __shared__ unsigned int sh_prefix, sh_k, sh_cnt, sh_eq;
  __shared__ int eqlist[1024];
  const int tid = threadIdx.x, e = blockIdx.x;
  const float* row = scores + (size_t)e * Tn;
  for (int i = 0; i < Tn / 256; ++i)
    keys[tid + i * 256] = __float_as_uint(row[tid + i * 256]);
  if (tid == 0) { sh_prefix = 0u; sh_k = CAPn; }
  __syncthreads();
  for (int shift = 24; shift >= 0; shift -= 8) {
    hist[tid] = 0u;
    __syncthreads();
    unsigned int prefix = sh_prefix;
    unsigned int mask = (shift == 24) ? 0u : (0xFFFFFFFFu << (shift + 8));
    for (int i = 0; i < Tn / 256; ++i) {
      unsigned int kk = keys[tid + i * 256];
      if ((kk & mask) == prefix) atomicAdd(&hist[(kk >> shift) & 255], 1u);
    }
    __syncthreads();
    if (tid == 0) {
      unsigned int k = sh_k, c = 0; int b;
      for (b = 255; b >= 0; --b) { c += hist[b]; if (c >= k) break; }
      sh_k = k - (c - hist[b]);
      sh_prefix = prefix | ((unsigned int)b << shift);
    }
    __syncthreads();
  }
  const unsigned int thr = sh_prefix;
  if (tid == 0) { sh_cnt = 0u; sh_eq = 0u; }
  __syncthreads();
  const int base = e * CAPn;
  for (int i = 0; i < Tn / 256; ++i) {
    int t = tid + i * 256;
    unsigned int kk = keys[t];
    if (kk > thr) {
      unsigned int p = atomicAdd(&sh_cnt, 1u);
      ids[base + p] = t;
      oscore[base + p] = __uint_as_float(kk);
    } else if (kk == thr) {
      unsigned int p = atomicAdd(&sh_eq, 1u);
      if (p < 1024u) eqlist[p] = t;
    }
  }
  __syncthreads();
  if (tid == 0) {
    int need = CAPn - (int)sh_cnt;
    int m = (int)sh_eq; if (m > 1024) m = 1024;
    for (int j = 0; j < need; ++j) {
      int best = 1 << 30, bi = 0;
      for (int i2 = 0; i2 < m; ++i2)
        if (eqlist[i2] < best) { best = eqlist[i2]; bi = i2; }
      eqlist[bi] = 1 << 30;
      ids[base + (int)sh_cnt + j] = best;
      oscore[base + (int)sh_cnt + j] = __uint_as_float(thr);
    }
  }
}

// =====================================================================
// Round-2 GEMMs (2-phase, 128x128, 16x16x32 MFMA, global_load_lds +
// both-sides XOR swizzle, bm-fastest + XCD chunk swizzle) with fused
// weight-convert blocks: blockIdx >= gemmN runs grid-stride fp32->bf16.
// =====================================================================

// GLU: H = bf16( silu(A@Wg^T + bg) * (A@Wu^T + bu) ), K = Dn
template <bool GATHER>
__global__ __launch_bounds__(256, 2) void kglu_bf(
    const unsigned short* __restrict__ X, const int* __restrict__ idsg,
    const unsigned short* __restrict__ Wg, const unsigned short* __restrict__ Wu,
    const float* __restrict__ biasg, const float* __restrict__ biasu,
    unsigned short* __restrict__ H, int N, int Mz, int MB, int NB,
    int gemmN,
    const float* __restrict__ cS1, unsigned short* __restrict__ cD1, int cn1,
    const float* __restrict__ cS2, unsigned short* __restrict__ cD2, int cn2) {
  constexpr int K = Dn;
  __shared__ alignas(16) unsigned char sA[16384];
  __shared__ alignas(16) unsigned char sB1[16384];
  __shared__ alignas(16) unsigned char sB2[16384];
  __shared__ int sIds[128];
  const int tid = threadIdx.x;
  const int bid = blockIdx.x;
  if (bid >= gemmN) {
    conv_blocks(bid - gemmN, gridDim.x - gemmN, tid, cS1, cD1, cn1, cS2, cD2, cn2);
    return;
  }
  const int cpx = gemmN >> 3;
  const int swz = (bid & 7) * cpx + (bid >> 3);
  const int bm = swz % MB;
  const int bn = (swz / MB) % NB;
  const int z  = swz / (MB * NB);
  const int lane = tid & 63, w = tid >> 6;
  const int wm = w >> 1, wn = w & 1;
  const int lrow = lane & 15, lk = lane >> 4;
  const int row0 = bm * 128;

  if (tid < 128) sIds[tid] = GATHER ? idsg[z * CAPn + row0 + tid] : (row0 + tid);
  __syncthreads();

  const int lr = lane >> 3;
  const int lc = lane & 7;
  const int srcb = ((lc ^ lr) << 4);
  const unsigned char* Xb = (const unsigned char*)X;
  const unsigned char* Gb = (const unsigned char*)Wg + (size_t)z * N * (K * 2);
  const unsigned char* Ub = (const unsigned char*)Wu + (size_t)z * N * (K * 2);
  const unsigned char* aP[4];
#pragma unroll
  for (int i = 0; i < 4; ++i) {
    int ar = w * 32 + 8 * i + lr;
    aP[i] = Xb + (size_t)sIds[ar] * (K * 2) + srcb;
  }
  const int br0 = bn * 128 + w * 32 + lr;
  const unsigned char* gP0 = Gb + (size_t)br0 * (K * 2) + srcb;
  const unsigned char* uP0 = Ub + (size_t)br0 * (K * 2) + srcb;

  f32x4 accG[4][4], accU[4][4];
#pragma unroll
  for (int m = 0; m < 4; ++m)
#pragma unroll
    for (int n = 0; n < 4; ++n) {
      accG[m][n] = {0.f, 0.f, 0.f, 0.f};
      accU[m][n] = {0.f, 0.f, 0.f, 0.f};
    }

  for (int k0b = 0; k0b < K * 2; k0b += 128) {
    __syncthreads();
#pragma unroll
    for (int i = 0; i < 4; ++i) {
      unsigned ldsoff = (unsigned)(w * 32 + 8 * i) * 128u;
      gload16(aP[i] + k0b, sA + ldsoff);
      gload16(gP0 + (size_t)i * 8 * (K * 2) + k0b, sB1 + ldsoff);
      gload16(uP0 + (size_t)i * 8 * (K * 2) + k0b, sB2 + ldsoff);
    }
    __syncthreads();
#pragma unroll
    for (int ks = 0; ks < 2; ++ks) {
      const int swb = (((ks * 4 + lk) ^ (lrow & 7)) << 4);
      bf16x8 av[4], gv[4], uv[4];
#pragma unroll
      for (int m = 0; m < 4; ++m)
        av[m] = *(const bf16x8*)(sA + (wm * 64 + m * 16 + lrow) * 128 + swb);
#pragma unroll
      for (int n = 0; n < 4; ++n) {
        gv[n] = *(const bf16x8*)(sB1 + (wn * 64 + n * 16 + lrow) * 128 + swb);
        uv[n] = *(const bf16x8*)(sB2 + (wn * 64 + n * 16 + lrow) * 128 + swb);
      }
#pragma unroll
      for (int m = 0; m < 4; ++m)
#pragma unroll
        for (int n = 0; n < 4; ++n) {
          accG[m][n] = __builtin_amdgcn_mfma_f32_16x16x32_bf16(av[m], gv[n], accG[m][n], 0, 0, 0);
          accU[m][n] = __builtin_amdgcn_mfma_f32_16x16x32_bf16(av[m], uv[n], accU[m][n], 0, 0, 0);
        }
    }
  }
#pragma unroll
  for (int n = 0; n < 4; ++n) {
    int col = bn * 128 + wn * 64 + n * 16 + lrow;
    float bg = biasg ? biasg[(size_t)z * N + col] : 0.f;
    float bu = biasu ? biasu[(size_t)z * N + col] : 0.f;
#pragma unroll
    for (int m = 0; m < 4; ++m) {
#pragma unroll
      for (int j = 0; j < 4; ++j) {
        float g = accG[m][n][j] + bg;
        float u = accU[m][n][j] + bu;
        float h = g / (1.f + __expf(-g)) * u;
        int row = row0 + wm * 64 + m * 16 + lk * 4 + j;
        H[(size_t)z * Mz * N + (size_t)row * N + col] = f2bf(h);
      }
    }
  }
}

// down: Out = A@W^T (+bias, xscore scatter-add when SCATTER), N = Dn
template <int K, bool SCATTER>
__global__ __launch_bounds__(256, 2) void kdown_bf(
    const unsigned short* __restrict__ Hin, const unsigned short* __restrict__ W,
    const float* __restrict__ bias, const int* __restrict__ idsg,
    const float* __restrict__ scg, float* __restrict__ Out, int Mz, int MB, int NB) {
  constexpr int N = Dn;
  __shared__ alignas(16) unsigned char sA[16384];
  __shared__ alignas(16) unsigned char sB[16384];
  __shared__ int sIds[128];
  __shared__ float sSc[128];
  const int tid = threadIdx.x;
  const int nwg = gridDim.x;
  const int cpx = nwg >> 3;
  const int bid = blockIdx.x;
  const int swz = (bid & 7) * cpx + (bid >> 3);
  const int bm = swz % MB;
  const int bn = (swz / MB) % NB;
  const int z  = swz / (MB * NB);
  const int lane = tid & 63, w = tid >> 6;
  const int wm = w >> 1, wn = w & 1;
  const int lrow = lane & 15, lk = lane >> 4;
  const int row0 = bm * 128;

  if (SCATTER && tid < 128) {
    sIds[tid] = idsg[z * CAPn + row0 + tid];
    sSc[tid] = scg[z * CAPn + row0 + tid];
  }
  __syncthreads();

  const int lr = lane >> 3;
  const int lc = lane & 7;
  const int srcb = ((lc ^ lr) << 4);
  const unsigned char* Ab = (const unsigned char*)Hin + (size_t)z * Mz * (K * 2);
  const unsigned char* Wb = (const unsigned char*)W + (size_t)z * N * (K * 2);
  const int ar0 = row0 + w * 32 + lr;
  const int br0 = bn * 128 + w * 32 + lr;
  const unsigned char* aP0 = Ab + (size_t)ar0 * (K * 2) + srcb;
  const unsigned char* bP0 = Wb + (size_t)br0 * (K * 2) + srcb;

  f32x4 acc[4][4];
#pragma unroll
  for (int m = 0; m < 4; ++m)
#pragma unroll
    for (int n = 0; n < 4; ++n) acc[m][n] = {0.f, 0.f, 0.f, 0.f};

  for (int k0b = 0; k0b < K * 2; k0b += 128) {
    __syncthreads();
#pragma unroll
    for (int i = 0; i < 4; ++i) {
      unsigned ldsoff = (unsigned)(w * 32 + 8 * i) * 128u;
      gload16(aP0 + (size_t)i * 8 * (K * 2) + k0b, sA + ldsoff);
      gload16(bP0 + (size_t)i * 8 * (K * 2) + k0b, sB + ldsoff);
    }
    __syncthreads();
#pragma unroll
    for (int ks = 0; ks < 2; ++ks) {
      const int swb = (((ks * 4 + lk) ^ (lrow & 7)) << 4);
      bf16x8 av[4], bv[4];
#pragma unroll
      for (int m = 0; m < 4; ++m)
        av[m] = *(const bf16x8*)(sA + (wm * 64 + m * 16 + lrow) * 128 + swb);
#pragma unroll
      for (int n = 0; n < 4; ++n)
        bv[n] = *(const bf16x8*)(sB + (wn * 64 + n * 16 + lrow) * 128 + swb);
#pragma unroll
      for (int m = 0; m < 4; ++m)
#pragma unroll
        for (int n = 0; n < 4; ++n)
          acc[m][n] = __builtin_amdgcn_mfma_f32_16x16x32_bf16(av[m], bv[n], acc[m][n], 0, 0, 0);
    }
  }
#pragma unroll
  for (int n = 0; n < 4; ++n) {
    int col = bn * 128 + wn * 64 + n * 16 + lrow;
    float bvv = bias ? bias[(size_t)z * N + col] : 0.f;
#pragma unroll
    for (int m = 0; m < 4; ++m) {
#pragma unroll
      for (int j = 0; j < 4; ++j) {
        int rl = wm * 64 + m * 16 + lk * 4 + j;
        float v = acc[m][n][j] + bvv;
        if (SCATTER) {
          atomicAdd(Out + (size_t)sIds[rl] * Dn + col, sSc[rl] * v);
        } else {
          Out[(size_t)(row0 + rl) * Dn + col] = v;
        }
      }
    }
  }
}

extern "C" void kernel_launch(void* const* d_in, const int* in_sizes, int n_in,
                              void* d_out, int out_size, void* d_ws, size_t ws_size,
                              hipStream_t stream) {
  const float* x      = (const float*)d_in[0];
  const float* gate_w = (const float*)d_in[1];
  const float* up_w   = (const float*)d_in[2];
  const float* up_b   = (const float*)d_in[3];
  const float* gw     = (const float*)d_in[4];
  const float* gb     = (const float*)d_in[5];
  const float* down_w = (const float*)d_in[6];
  const float* down_b = (const float*)d_in[7];
  const float* shg    = (const float*)d_in[8];
  const float* shu    = (const float*)d_in[9];
  const float* shd    = (const float*)d_in[10];
  float* out = (float*)d_out;

  const size_t H_BYTES  = (size_t)En * CAPn * Fn * 2;   // 134 MiB
  const size_t XB_BYTES = (size_t)Tn * Dn * 2;          // 16 MiB
  const size_t WE_BYTES = (size_t)En * Fn * Dn * 2;     // 128 MiB each
  const size_t SH_BYTES = (size_t)SHn * Dn * 2;         // 4 MiB each
  const size_t SC_BYTES = (size_t)En * Tn * 4;
  const size_t ID_BYTES = (size_t)En * CAPn * 4;
  const size_t need = H_BYTES + XB_BYTES + 3 * WE_BYTES + 3 * SH_BYTES +
                      SC_BYTES + 2 * ID_BYTES;
  if (ws_size < need) return;

  char* p = (char*)d_ws;
  unsigned short* H    = (unsigned short*)p; p += H_BYTES;
  unsigned short* xb   = (unsigned short*)p; p += XB_BYTES;
  unsigned short* upb  = (unsigned short*)p; p += WE_BYTES;
  unsigned short* gwb  = (unsigned short*)p; p += WE_BYTES;
  unsigned short* dwb  = (unsigned short*)p; p += WE_BYTES;
  unsigned short* shgb = (unsigned short*)p; p += SH_BYTES;
  unsigned short* shub = (unsigned short*)p; p += SH_BYTES;
  unsigned short* shdb = (unsigned short*)p; p += SH_BYTES;
  float* scores = (float*)p; p += SC_BYTES;
  int* ids      = (int*)p;  p += ID_BYTES;
  float* osc    = (float*)p;

  constexpr int NWE8 = En * Fn * Dn / 8;   // 8 bf16-chunks per expert-weight tensor

  // K1: scores + x->bf16, plus shared-weight converts in extra blocks
  kscores_cvt<<<Tn + 256, 256, 0, stream>>>(x, gate_w, scores, xb,
                                            shg, shgb, shu, shub, shd, shdb);
  // K2: routing
  kselect<<<En, 256, 0, stream>>>(scores, ids, osc);

  // K3: shared GLU (1024 gemm blocks) + convert up_w->upb, gw->gwb (2048 conv blocks)
  kglu_bf<false><<<(Tn / 128) * (SHn / 128) + 2048, 256, 0, stream>>>(
      xb, nullptr, shgb, shub, nullptr, nullptr, H, SHn, Tn, Tn / 128, SHn / 128,
      (Tn / 128) * (SHn / 128), up_w, upb, NWE8, gw, gwb, NWE8);

  // K4: shared down (dense store covers all of d_out)
  kdown_bf<SHn, false><<<(Tn / 128) * (Dn / 128), 256, 0, stream>>>(
      H, shdb, nullptr, nullptr, nullptr, out, Tn, Tn / 128, Dn / 128);

  // K5: expert GLU (4096 gemm blocks) + convert down_w->dwb (1024 conv blocks)
  kglu_bf<true><<<(CAPn / 128) * (Fn / 128) * En + 1024, 256, 0, stream>>>(
      xb, ids, gwb, upb, gb, up_b, H, Fn, CAPn, CAPn / 128, Fn / 128,
      (CAPn / 128) * (Fn / 128) * En, down_w, dwb, NWE8, nullptr, nullptr, 0);

  // K6: expert down (scatter atomic-add * score)
  kdown_bf<Fn, true><<<(CAPn / 128) * (Dn / 128) * En, 256, 0, stream>>>(
      H, dwb, down_b, ids, osc, out, CAPn, CAPn / 128, Dn / 128);
}